// Round 6
// baseline (1393.653 us; speedup 1.0000x reference)
//
#include <hip/hip_runtime.h>

typedef unsigned short u16;
typedef __attribute__((ext_vector_type(8))) __bf16 bf16x8;
typedef __attribute__((ext_vector_type(4))) float f32x4;
typedef __attribute__((ext_vector_type(4))) unsigned short u16x4;
typedef __attribute__((ext_vector_type(8))) unsigned short u16x8;

#define GLOBAL_AS __attribute__((address_space(1)))
#define LDS_AS __attribute__((address_space(3)))

__device__ __forceinline__ void gload_lds16(const void* g, void* l) {
    __builtin_amdgcn_global_load_lds((const GLOBAL_AS void*)g, (LDS_AS void*)l, 16, 0, 0);
}

__device__ __forceinline__ u16 f2bf(float f) {
    union { float f; unsigned u; } x; x.f = f;
    unsigned r = x.u + 0x7FFFu + ((x.u >> 16) & 1u);
    return (u16)(r >> 16);
}
__device__ __forceinline__ float bf2f(u16 h) {
    union { unsigned u; float f; } x; x.u = ((unsigned)h) << 16;
    return x.f;
}
struct BfPair { u16 h, l; };
// fp32 -> (hi,lo) bf16 pair; hi+lo reproduces v to ~2^-17 relative.
__device__ __forceinline__ BfPair split2(float v) {
    BfPair p;
    p.h = f2bf(v);
    p.l = f2bf(v - bf2f(p.h));
    return p;
}

#define TM 128
#define TN 128
#define BK 64

// ---------------- projection GEMM: C = alpha * A(f32,MxK) @ B(f32,NxK)^T,
// split-bf16 output (Ch hi, Cl lo). Batched; strides in BYTES.
__global__ __launch_bounds__(256) void gemm_proj(
    const float* __restrict__ A, const float* __restrict__ B,
    u16* __restrict__ Ch, u16* __restrict__ Cl,
    int M, int N, int K, size_t sAb, size_t sBb, size_t sCb, float alpha)
{
    __shared__ u16 As[TM * BK];
    __shared__ u16 Bs[TN * BK];

    const int z = blockIdx.z;
    const float* Ab = (const float*)((const char*)A + (size_t)z * sAb);
    const float* Bb = (const float*)((const char*)B + (size_t)z * sBb);

    const int n0 = blockIdx.x * TN;
    const int m0 = blockIdx.y * TM;
    const int tid = threadIdx.x;
    const int lane = tid & 63;
    const int wave = tid >> 6;
    const int wm = (wave >> 1) * 64;
    const int wn = (wave & 1) * 64;
    const int quad = lane >> 4;
    const int lrow = lane & 15;

    f32x4 acc[4][4] = {};

    for (int k0 = 0; k0 < K; k0 += BK) {
        #pragma unroll
        for (int r = 0; r < 4; ++r) {
            const int wbase = r * 4096 + wave * 1024;
            const int o = wbase + lane * 16;
            const int row = o >> 7;
            const int ce = (o & 127) >> 1;
            {
                const float* g = Ab + (size_t)(m0 + row) * K + k0 + ce;
                f32x4 v0 = *(const f32x4*)g;
                f32x4 v1 = *(const f32x4*)(g + 4);
                u16x8 w;
                #pragma unroll
                for (int e = 0; e < 4; ++e) { w[e] = f2bf(v0[e]); w[e + 4] = f2bf(v1[e]); }
                *(u16x8*)((char*)As + o) = w;
            }
            {
                const float* g = Bb + (size_t)(n0 + row) * K + k0 + ce;
                f32x4 v0 = *(const f32x4*)g;
                f32x4 v1 = *(const f32x4*)(g + 4);
                u16x8 w;
                #pragma unroll
                for (int e = 0; e < 4; ++e) { w[e] = f2bf(v0[e]); w[e + 4] = f2bf(v1[e]); }
                *(u16x8*)((char*)Bs + o) = w;
            }
        }
        __syncthreads();

        #pragma unroll
        for (int kk = 0; kk < BK; kk += 32) {
            bf16x8 af[4], bfr[4];
            #pragma unroll
            for (int t = 0; t < 4; ++t) {
                af[t]  = *(const bf16x8*)&As[(wm + t * 16 + lrow) * BK + kk + quad * 8];
                bfr[t] = *(const bf16x8*)&Bs[(wn + t * 16 + lrow) * BK + kk + quad * 8];
            }
            #pragma unroll
            for (int ti = 0; ti < 4; ++ti)
                #pragma unroll
                for (int tj = 0; tj < 4; ++tj)
                    acc[ti][tj] = __builtin_amdgcn_mfma_f32_16x16x32_bf16(
                        af[ti], bfr[tj], acc[ti][tj], 0, 0, 0);
        }
        __syncthreads();
    }

    u16* Chb = (u16*)((char*)Ch + (size_t)z * sCb);
    u16* Clb = (u16*)((char*)Cl + (size_t)z * sCb);
    #pragma unroll
    for (int ti = 0; ti < 4; ++ti)
        #pragma unroll
        for (int tj = 0; tj < 4; ++tj) {
            const int nn = n0 + wn + tj * 16 + lrow;
            #pragma unroll
            for (int r2 = 0; r2 < 4; ++r2) {
                const int mm = m0 + wm + ti * 16 + quad * 4 + r2;
                BfPair p = split2(acc[ti][tj][r2] * alpha);
                Chb[(size_t)mm * N + nn] = p.h;
                Clb[(size_t)mm * N + nn] = p.l;
            }
        }
}

// ---------------- split x split GEMM (3-term): C = (Ah+Al) @ (Bh+Bl)^T, drop Al*Bl.
// OSPLIT: write split-bf16 (C,C2) else fp32 (C).
template <bool OSPLIT>
__global__ __launch_bounds__(256) void gemm_ll(
    const u16* __restrict__ Ah, const u16* __restrict__ Al,
    const u16* __restrict__ Bh, const u16* __restrict__ Bl,
    void* __restrict__ C, void* __restrict__ C2,
    int M, int N, int K, size_t sAb, size_t sBb, size_t sCb)
{
    __shared__ u16 Ash[TM * BK];
    __shared__ u16 Asl[TM * BK];
    __shared__ u16 Bsh[TN * BK];
    __shared__ u16 Bsl[TN * BK];

    const int z = blockIdx.z;
    const u16* Ahb = (const u16*)((const char*)Ah + (size_t)z * sAb);
    const u16* Alb = (const u16*)((const char*)Al + (size_t)z * sAb);
    const u16* Bhb = (const u16*)((const char*)Bh + (size_t)z * sBb);
    const u16* Blb = (const u16*)((const char*)Bl + (size_t)z * sBb);

    const int n0 = blockIdx.x * TN;
    const int m0 = blockIdx.y * TM;
    const int tid = threadIdx.x;
    const int lane = tid & 63;
    const int wave = tid >> 6;
    const int wm = (wave >> 1) * 64;
    const int wn = (wave & 1) * 64;
    const int quad = lane >> 4;
    const int lrow = lane & 15;

    f32x4 acc[4][4] = {};

    for (int k0 = 0; k0 < K; k0 += BK) {
        #pragma unroll
        for (int r = 0; r < 4; ++r) {
            const int wbase = r * 4096 + wave * 1024;
            const int o = wbase + lane * 16;
            const int row = o >> 7;
            const int ce = (o & 127) >> 1;
            const size_t ao = (size_t)(m0 + row) * K + k0 + ce;
            const size_t bo = (size_t)(n0 + row) * K + k0 + ce;
            gload_lds16(Ahb + ao, (char*)Ash + wbase);
            gload_lds16(Alb + ao, (char*)Asl + wbase);
            gload_lds16(Bhb + bo, (char*)Bsh + wbase);
            gload_lds16(Blb + bo, (char*)Bsl + wbase);
        }
        __syncthreads();

        #pragma unroll
        for (int kk = 0; kk < BK; kk += 32) {
            bf16x8 ah[4], al[4], bh[4], bl[4];
            #pragma unroll
            for (int t = 0; t < 4; ++t) {
                const int ra = (wm + t * 16 + lrow) * BK + kk + quad * 8;
                const int rb = (wn + t * 16 + lrow) * BK + kk + quad * 8;
                ah[t] = *(const bf16x8*)&Ash[ra];
                al[t] = *(const bf16x8*)&Asl[ra];
                bh[t] = *(const bf16x8*)&Bsh[rb];
                bl[t] = *(const bf16x8*)&Bsl[rb];
            }
            #pragma unroll
            for (int ti = 0; ti < 4; ++ti)
                #pragma unroll
                for (int tj = 0; tj < 4; ++tj) {
                    acc[ti][tj] = __builtin_amdgcn_mfma_f32_16x16x32_bf16(
                        al[ti], bh[tj], acc[ti][tj], 0, 0, 0);
                    acc[ti][tj] = __builtin_amdgcn_mfma_f32_16x16x32_bf16(
                        ah[ti], bl[tj], acc[ti][tj], 0, 0, 0);
                    acc[ti][tj] = __builtin_amdgcn_mfma_f32_16x16x32_bf16(
                        ah[ti], bh[tj], acc[ti][tj], 0, 0, 0);
                }
        }
        __syncthreads();
    }

    if (OSPLIT) {
        u16* Chb = (u16*)((char*)C + (size_t)z * sCb);
        u16* Clb = (u16*)((char*)C2 + (size_t)z * sCb);
        #pragma unroll
        for (int ti = 0; ti < 4; ++ti)
            #pragma unroll
            for (int tj = 0; tj < 4; ++tj) {
                const int nn = n0 + wn + tj * 16 + lrow;
                #pragma unroll
                for (int r2 = 0; r2 < 4; ++r2) {
                    const int mm = m0 + wm + ti * 16 + quad * 4 + r2;
                    BfPair p = split2(acc[ti][tj][r2]);
                    Chb[(size_t)mm * N + nn] = p.h;
                    Clb[(size_t)mm * N + nn] = p.l;
                }
            }
    } else {
        float* Cb = (float*)((char*)C + (size_t)z * sCb);
        #pragma unroll
        for (int ti = 0; ti < 4; ++ti)
            #pragma unroll
            for (int tj = 0; tj < 4; ++tj) {
                const int nn = n0 + wn + tj * 16 + lrow;
                #pragma unroll
                for (int r2 = 0; r2 < 4; ++r2) {
                    const int mm = m0 + wm + ti * 16 + quad * 4 + r2;
                    Cb[(size_t)mm * N + nn] = acc[ti][tj][r2];
                }
            }
    }
}

// ---------------- final GEMM (2-term): C_f32 = (Ah+Al) @ Bf32^T (B bf16-valued).
__global__ __launch_bounds__(256) void gemm_fin(
    const u16* __restrict__ Ah, const u16* __restrict__ Al,
    const float* __restrict__ B, float* __restrict__ C,
    int M, int N, int K)
{
    __shared__ u16 Ash[TM * BK];
    __shared__ u16 Asl[TM * BK];
    __shared__ u16 Bs[TN * BK];

    const int n0 = blockIdx.x * TN;
    const int m0 = blockIdx.y * TM;
    const int tid = threadIdx.x;
    const int lane = tid & 63;
    const int wave = tid >> 6;
    const int wm = (wave >> 1) * 64;
    const int wn = (wave & 1) * 64;
    const int quad = lane >> 4;
    const int lrow = lane & 15;

    f32x4 acc[4][4] = {};

    for (int k0 = 0; k0 < K; k0 += BK) {
        #pragma unroll
        for (int r = 0; r < 4; ++r) {
            const int wbase = r * 4096 + wave * 1024;
            const int o = wbase + lane * 16;
            const int row = o >> 7;
            const int ce = (o & 127) >> 1;
            const size_t ao = (size_t)(m0 + row) * K + k0 + ce;
            gload_lds16(Ah + ao, (char*)Ash + wbase);
            gload_lds16(Al + ao, (char*)Asl + wbase);
            {
                const float* g = B + (size_t)(n0 + row) * K + k0 + ce;
                f32x4 v0 = *(const f32x4*)g;
                f32x4 v1 = *(const f32x4*)(g + 4);
                u16x8 w;
                #pragma unroll
                for (int e = 0; e < 4; ++e) { w[e] = f2bf(v0[e]); w[e + 4] = f2bf(v1[e]); }
                *(u16x8*)((char*)Bs + o) = w;
            }
        }
        __syncthreads();

        #pragma unroll
        for (int kk = 0; kk < BK; kk += 32) {
            bf16x8 ah[4], al[4], bfr[4];
            #pragma unroll
            for (int t = 0; t < 4; ++t) {
                const int ra = (wm + t * 16 + lrow) * BK + kk + quad * 8;
                ah[t] = *(const bf16x8*)&Ash[ra];
                al[t] = *(const bf16x8*)&Asl[ra];
                bfr[t] = *(const bf16x8*)&Bs[(wn + t * 16 + lrow) * BK + kk + quad * 8];
            }
            #pragma unroll
            for (int ti = 0; ti < 4; ++ti)
                #pragma unroll
                for (int tj = 0; tj < 4; ++tj) {
                    acc[ti][tj] = __builtin_amdgcn_mfma_f32_16x16x32_bf16(
                        al[ti], bfr[tj], acc[ti][tj], 0, 0, 0);
                    acc[ti][tj] = __builtin_amdgcn_mfma_f32_16x16x32_bf16(
                        ah[ti], bfr[tj], acc[ti][tj], 0, 0, 0);
                }
        }
        __syncthreads();
    }

    #pragma unroll
    for (int ti = 0; ti < 4; ++ti)
        #pragma unroll
        for (int tj = 0; tj < 4; ++tj) {
            const int nn = n0 + wn + tj * 16 + lrow;
            #pragma unroll
            for (int r2 = 0; r2 < 4; ++r2) {
                const int mm = m0 + wm + ti * 16 + quad * 4 + r2;
                C[(size_t)mm * N + nn] = acc[ti][tj][r2];
            }
        }
}

// Row softmax over Lh (8192 rows x 1024 fp32), diag (j == row%1024) -> -inf.
// Split-bf16 output.
__global__ __launch_bounds__(256) void softmax_split(
    const float* __restrict__ Lh, u16* __restrict__ Th, u16* __restrict__ Tl)
{
    const int lane = threadIdx.x & 63;
    const int wave = threadIdx.x >> 6;
    const size_t row = (size_t)blockIdx.x * 4 + wave;
    const int i = (int)(row & 1023);
    const float* src = Lh + row * 1024;
    const float NEG = -__builtin_inff();

    float v[16];
    float mx = NEG;
    #pragma unroll
    for (int cc = 0; cc < 4; ++cc) {
        f32x4 x = *(const f32x4*)(src + cc * 256 + lane * 4);
        #pragma unroll
        for (int e = 0; e < 4; ++e) {
            const int j = cc * 256 + lane * 4 + e;
            const float val = (j == i) ? NEG : x[e];
            v[cc * 4 + e] = val;
            mx = fmaxf(mx, val);
        }
    }
    #pragma unroll
    for (int off = 32; off > 0; off >>= 1) mx = fmaxf(mx, __shfl_xor(mx, off, 64));
    float s = 0.f;
    #pragma unroll
    for (int k = 0; k < 16; ++k) { v[k] = __expf(v[k] - mx); s += v[k]; }
    #pragma unroll
    for (int off = 32; off > 0; off >>= 1) s += __shfl_xor(s, off, 64);
    const float inv = 1.0f / s;

    #pragma unroll
    for (int cc = 0; cc < 4; ++cc) {
        u16x4 wh, wl;
        #pragma unroll
        for (int e = 0; e < 4; ++e) {
            BfPair p = split2(v[cc * 4 + e] * inv);
            wh[e] = p.h;
            wl[e] = p.l;
        }
        *(u16x4*)(Th + row * 1024 + cc * 256 + lane * 4) = wh;
        *(u16x4*)(Tl + row * 1024 + cc * 256 + lane * 4) = wl;
    }
}

// attn_f32[b][i][j] = (Th+Tl)[b][j][i]
__global__ __launch_bounds__(256) void transpose_attn_f32(
    const u16* __restrict__ Th, const u16* __restrict__ Tl, float* __restrict__ A)
{
    __shared__ float tile[64][65];
    const int bz = blockIdx.z;
    const int x0 = blockIdx.x * 64;
    const int y0 = blockIdx.y * 64;
    const size_t base = (size_t)bz * 1024 * 1024;
    float* dst = A + base;
    const int t = threadIdx.x;
    const int rt = t >> 4;
    const int c4 = (t & 15) * 4;

    #pragma unroll
    for (int p = 0; p < 4; ++p) {
        const int r = p * 16 + rt;
        const size_t off = base + (size_t)(y0 + r) * 1024 + x0 + c4;
        u16x4 vh = *(const u16x4*)(Th + off);
        u16x4 vl = *(const u16x4*)(Tl + off);
        #pragma unroll
        for (int e = 0; e < 4; ++e) tile[r][c4 + e] = bf2f(vh[e]) + bf2f(vl[e]);
    }
    __syncthreads();
    #pragma unroll
    for (int p = 0; p < 4; ++p) {
        const int a = p * 16 + rt;
        f32x4 w;
        #pragma unroll
        for (int e = 0; e < 4; ++e) w[e] = tile[c4 + e][a];
        *(f32x4*)(dst + (size_t)(x0 + a) * 1024 + y0 + c4) = w;
    }
}

extern "C" void kernel_launch(void* const* d_in, const int* in_sizes, int n_in,
                              void* d_out, int out_size, void* d_ws, size_t ws_size,
                              hipStream_t stream) {
    const float* y  = (const float*)d_in[0];   // (8,1024,2048) fp32
    const float* Wk = (const float*)d_in[1];   // (2048,2048)
    const float* Wq = (const float*)d_in[2];
    const float* Wv = (const float*)d_in[3];
    const float* Wo = (const float*)d_in[4];

    const int b = 8, n = 1024, d = 2048;
    const int MB = b * n;                 // 8192
    const size_t MiB = 1024 * 1024;

    // d_out (fp32, 96 MiB): out [0,64 MiB), attn [64,96 MiB)
    float* outF = (float*)d_out;
    float* attF = outF + (size_t)MB * d;
    // Scratch inside out region (dead before final GEMM):
    u16*   Th = (u16*)d_out;                       // [0,16 MiB)
    u16*   Tl = (u16*)((char*)d_out + 16 * MiB);   // [16,32 MiB)
    float* Lh = (float*)((char*)d_out + 32 * MiB); // [32,64 MiB)

    // ws (peak 128 MiB; R2/R3 identical-output proves >=128 MiB usable)
    char* ws = (char*)d_ws;
    u16* Kh = (u16*)ws;               // [0,32)
    u16* Kl = (u16*)(ws + 32 * MiB);  // [32,64)
    u16* Qh = (u16*)(ws + 64 * MiB);  // [64,96)
    u16* Ql = (u16*)(ws + 96 * MiB);  // [96,128)
    u16* Vh = (u16*)ws;               // over Kh (dead after logits)
    u16* Vl = (u16*)(ws + 32 * MiB);  // over Kl
    u16* Oh = (u16*)(ws + 64 * MiB);  // over Qh (dead after logits)
    u16* Ol = (u16*)(ws + 96 * MiB);  // over Ql

    dim3 blk(256);
    // 1) K = y @ Wk^T  -> split
    gemm_proj<<<dim3(d / TN, MB / TM, 1), blk, 0, stream>>>(
        y, Wk, Kh, Kl, MB, d, d, 0, 0, 0, 1.0f);
    // 2) Q = 0.1 * y @ Wq^T -> split
    gemm_proj<<<dim3(d / TN, MB / TM, 1), blk, 0, stream>>>(
        y, Wq, Qh, Ql, MB, d, d, 0, 0, 0, 0.1f);
    // 3) Lt[b,i,j] = K_i.Q_j  (3-term split, fp32 out)
    gemm_ll<false><<<dim3(n / TN, n / TM, b), blk, 0, stream>>>(
        Kh, Kl, Qh, Ql, Lh, nullptr, n, n, d,
        (size_t)n * d * 2, (size_t)n * d * 2, (size_t)n * n * 4);
    // 4) T = row_softmax(Lt, diag) -> split
    softmax_split<<<dim3(MB / 4), blk, 0, stream>>>(Lh, Th, Tl);
    // 5) Vt[b,e,j] = Wv @ y_b^T -> split  (over Kh/Kl; dead)
    gemm_proj<<<dim3(n / TN, d / TM, b), blk, 0, stream>>>(
        Wv, y, Vh, Vl, d, n, d, 0, (size_t)n * d * 4, (size_t)d * n * 2, 1.0f);
    // 6) attn = (Th+Tl)^T as fp32
    transpose_attn_f32<<<dim3(16, 16, b), blk, 0, stream>>>(Th, Tl, attF);
    // 7) out0 = T @ Vt^T  (3-term split in, split out; over Qh/Ql; dead)
    gemm_ll<true><<<dim3(d / TN, n / TM, b), blk, 0, stream>>>(
        Th, Tl, Vh, Vl, Oh, Ol, n, d, n,
        (size_t)n * n * 2, (size_t)d * n * 2, (size_t)n * d * 2);
    // 8) out = out0 @ Wo^T (2-term, fp32 out; clobbers Th/Tl/Lh — dead)
    gemm_fin<<<dim3(d / TN, MB / TM, 1), blk, 0, stream>>>(
        Oh, Ol, Wo, outF, MB, d, d);
}